// Round 4
// baseline (240.241 us; speedup 1.0000x reference)
//
#include <hip/hip_runtime.h>
#include <math.h>

#define CC 128
#define NN 4096   // 16*16*16
#define BB 2
#define NGROUPS 32
#define CPG 4
#define GSIZE (CPG*NN)          // 16384 elements per (b, group)
#define KSPLIT 4

typedef __attribute__((ext_vector_type(8))) __bf16 bf16x8;
typedef __attribute__((ext_vector_type(4))) float floatx4;

__device__ __forceinline__ unsigned short f2bf(float f) {
  union { float f; unsigned u; } v; v.f = f;
  unsigned r = v.u + 0x7fff + ((v.u >> 16) & 1);   // RNE
  return (unsigned short)(r >> 16);
}
__device__ __forceinline__ float bf2f(unsigned short u) {
  return __uint_as_float(((unsigned)u) << 16);
}

// ---- stage 1: per-(b,g,chunk) partial sums. 256 blocks x 256 thr, 1 float4/thr ----
__global__ void gn_stats_kernel(const float* __restrict__ x, float2* __restrict__ stats) {
  int bid = blockIdx.x;                 // flat: ((b*32+g)*4 + chunk), chunk = 4096 floats
  int t = threadIdx.x;
  const float4* base = (const float4*)(x + (size_t)bid * 4096);
  float4 v = base[t];
  float s  = v.x + v.y + v.z + v.w;
  float ss = v.x*v.x + v.y*v.y + v.z*v.z + v.w*v.w;
  #pragma unroll
  for (int off = 1; off < 64; off <<= 1) {
    s  += __shfl_xor(s, off);
    ss += __shfl_xor(ss, off);
  }
  __shared__ float sred[4], ssred[4];
  if ((t & 63) == 0) { sred[t >> 6] = s; ssred[t >> 6] = ss; }
  __syncthreads();
  if (t == 0)
    stats[bid] = make_float2(sred[0]+sred[1]+sred[2]+sred[3],
                             ssred[0]+ssred[1]+ssred[2]+ssred[3]);
}

// ---- stage 2 (65 blocks): blocks 0-63 convert weights f32->bf16 (packed), block 64
// finalizes GN coeffs + scaled q bias ----
__global__ void prep_kernel(const float2* __restrict__ stats,
                            const float* __restrict__ gamma, const float* __restrict__ beta,
                            const float* __restrict__ wq, const float* __restrict__ bq,
                            const float* __restrict__ wk, const float* __restrict__ wv,
                            const float* __restrict__ wp,
                            float* __restrict__ ab_a, float* __restrict__ ab_b,
                            float* __restrict__ bqs,
                            unsigned short* __restrict__ wqb, unsigned short* __restrict__ wkb,
                            unsigned short* __restrict__ wvb, unsigned short* __restrict__ wpb) {
  const float sc = 0.08838834764831845f;   // 128^-0.5, folded into wq/bq
  int t = threadIdx.x;
  if (blockIdx.x == 64) {
    if (t < BB*NGROUPS) {
      float su = 0.f, ssq = 0.f;
      #pragma unroll
      for (int j = 0; j < 4; j++) { float2 p = stats[t*4 + j]; su += p.x; ssq += p.y; }
      float mean = su * (1.0f/GSIZE);
      float var  = ssq * (1.0f/GSIZE) - mean*mean;
      float rstd = rsqrtf(var + 1e-5f);
      int b = t / NGROUPS, g = t % NGROUPS;
      #pragma unroll
      for (int j = 0; j < 4; j++) {
        int c = g*4 + j;
        float a = rstd * gamma[c];
        ab_a[b*CC + c] = a;
        ab_b[b*CC + c] = beta[c] - mean * a;
      }
    }
    if (t < CC) bqs[t] = bq[t] * sc;
  } else {
    int i = blockIdx.x * 256 + t;        // 0..16383 float4 index; 4096 per weight
    int id = i >> 12, local = i & 4095;
    const float* src = id==0 ? wq : id==1 ? wk : id==2 ? wv : wp;
    unsigned short* dst = id==0 ? wqb : id==1 ? wkb : id==2 ? wvb : wpb;
    float s = (id == 0) ? sc : 1.0f;
    float4 v = ((const float4*)src)[local];
    unsigned p0 = (unsigned)f2bf(v.x*s) | ((unsigned)f2bf(v.y*s) << 16);
    unsigned p1 = (unsigned)f2bf(v.z*s) | ((unsigned)f2bf(v.w*s) << 16);
    ((uint2*)dst)[local] = make_uint2(p0, p1);
  }
}

// ---- q/k/v via MFMA, GN applied on the fly. q,k -> [B,N,C] bf16; v -> [B,C,N] bf16 ----
__global__ __launch_bounds__(256, 2) void qkv_kernel(
    const float* __restrict__ x,
    const float* __restrict__ ab_a, const float* __restrict__ ab_b,
    const unsigned short* __restrict__ wqb, const unsigned short* __restrict__ wkb,
    const unsigned short* __restrict__ wvb,
    const float* __restrict__ bqs, const float* __restrict__ bk, const float* __restrict__ bv,
    unsigned short* __restrict__ q, unsigned short* __restrict__ k, unsigned short* __restrict__ v) {
  int z = blockIdx.z, b = blockIdx.y, n0 = blockIdx.x * 32;
  const unsigned short* wsel = z==0 ? wqb : z==1 ? wkb : wvb;
  const float* bias          = z==0 ? bqs : z==1 ? bk  : bv;
  unsigned short* outp       = z==0 ? q   : z==1 ? k   : v;
  __shared__ unsigned short hs[32][130];   // normalized x tile, bf16 [n][c]
  __shared__ unsigned short vs[32][136];   // transpose staging (z==2 only)
  int t = threadIdx.x;
  #pragma unroll
  for (int j = 0; j < 16; j++) {
    int idx = j*256 + t;
    int c = idx >> 5, n = idx & 31;
    float xv = x[((size_t)b*CC + c)*NN + n0 + n];     // coalesced along n
    hs[n][c] = f2bf(ab_a[b*CC + c]*xv + ab_b[b*CC + c]);
  }
  __syncthreads();
  int w = t >> 6, lane = t & 63, quad = lane >> 4, c = lane & 15;
  int o0 = w * 32;
  floatx4 acc[2][2];
  #pragma unroll
  for (int rt = 0; rt < 2; rt++)
    #pragma unroll
    for (int ct = 0; ct < 2; ct++) acc[rt][ct] = (floatx4){0.f,0.f,0.f,0.f};
  #pragma unroll
  for (int ks = 0; ks < 4; ks++) {
    bf16x8 af[2];
    af[0] = *(const bf16x8*)&hs[c     ][ks*32 + quad*8];
    af[1] = *(const bf16x8*)&hs[16 + c][ks*32 + quad*8];
    #pragma unroll
    for (int ct = 0; ct < 2; ct++) {
      bf16x8 bfr = *(const bf16x8*)(wsel + (size_t)(o0 + ct*16 + c)*CC + ks*32 + quad*8);
      acc[0][ct] = __builtin_amdgcn_mfma_f32_16x16x32_bf16(af[0], bfr, acc[0][ct], 0, 0, 0);
      acc[1][ct] = __builtin_amdgcn_mfma_f32_16x16x32_bf16(af[1], bfr, acc[1][ct], 0, 0, 0);
    }
  }
  if (z < 2) {
    #pragma unroll
    for (int ct = 0; ct < 2; ct++) {
      float bi = bias[o0 + ct*16 + c];
      #pragma unroll
      for (int rt = 0; rt < 2; rt++)
        #pragma unroll
        for (int r = 0; r < 4; r++) {
          int n = rt*16 + quad*4 + r;
          outp[((size_t)b*NN + n0 + n)*CC + o0 + ct*16 + c] = f2bf(acc[rt][ct][r] + bi);
        }
    }
  } else {
    #pragma unroll
    for (int ct = 0; ct < 2; ct++) {
      float bi = bias[o0 + ct*16 + c];
      #pragma unroll
      for (int rt = 0; rt < 2; rt++)
        #pragma unroll
        for (int r = 0; r < 4; r++)
          vs[rt*16 + quad*4 + r][o0 + ct*16 + c] = f2bf(acc[rt][ct][r] + bi);
    }
    __syncthreads();
    int o = t >> 1, nh = (t & 1) * 16;
    unsigned pk[8];
    #pragma unroll
    for (int j2 = 0; j2 < 8; j2++) {
      unsigned lo = vs[nh + j2*2    ][o];
      unsigned hi = vs[nh + j2*2 + 1][o];
      pk[j2] = lo | (hi << 16);
    }
    uint4* dst = (uint4*)(outp + ((size_t)b*CC + o)*NN + n0 + nh);
    dst[0] = make_uint4(pk[0], pk[1], pk[2], pk[3]);
    dst[1] = make_uint4(pk[4], pk[5], pk[6], pk[7]);
  }
}

// ---- MFMA flash attention, split-K quarters, no-max softmax, partial outputs ----
// grid (128 q-tiles, 4 k-quarters, B) = 1024 blocks -> 4 blocks/CU (LDS 34.3 KB via
// Pl/obf union). No barriers in the main loop; one barrier guards the union aliasing.
__global__ __launch_bounds__(256, 4) void attn_kernel(
    const unsigned short* __restrict__ qm,  // [B,N,C] bf16, q-scale folded
    const unsigned short* __restrict__ km,  // [B,N,C] bf16
    const unsigned short* __restrict__ vm,  // [B,C,N] bf16
    unsigned short* __restrict__ Opart,     // [KSPLIT][B][N][C] bf16, unnormalized
    float* __restrict__ lpart) {            // [KSPLIT][B][N] f32
  int b    = blockIdx.z;
  int kh   = blockIdx.y;
  int row0 = blockIdx.x * 32;
  int t    = threadIdx.x;
  int w    = t >> 6, lane = t & 63, quad = lane >> 4, c = lane & 15;

  // union: main loop uses first 32x72 shorts of each wave's region as Pl;
  // epilogue reuses the full 32x132 region as obf (barrier-guarded).
  __shared__ unsigned short shmem[4][32][132];
  __shared__ float lred[4][32];
  unsigned short (*Pl)[72] = (unsigned short (*)[72])&shmem[w][0][0];

  bf16x8 qa[2][4];
  const unsigned short* qbase = qm + ((size_t)b*NN + row0)*CC;
  #pragma unroll
  for (int rt = 0; rt < 2; rt++)
    #pragma unroll
    for (int ks = 0; ks < 4; ks++)
      qa[rt][ks] = *(const bf16x8*)(qbase + (size_t)(rt*16 + c)*CC + ks*32 + quad*8);

  floatx4 O[2][8];
  #pragma unroll
  for (int rt = 0; rt < 2; rt++)
    #pragma unroll
    for (int ct = 0; ct < 8; ct++) O[rt][ct] = (floatx4){0.f,0.f,0.f,0.f};
  float lsum[2][4];
  #pragma unroll
  for (int rt = 0; rt < 2; rt++)
    #pragma unroll
    for (int r = 0; r < 4; r++) lsum[rt][r] = 0.f;

  const unsigned short* kb0 = km + (size_t)b*NN*CC;
  const unsigned short* vb0 = vm + (size_t)b*CC*NN;

  for (int it = 0; it < NN/KSPLIT/256; it++) {
    int mbase = kh*(NN/KSPLIT) + it*256 + w*64;
    floatx4 S[2][4];
    #pragma unroll
    for (int rt = 0; rt < 2; rt++)
      #pragma unroll
      for (int ct = 0; ct < 4; ct++) S[rt][ct] = (floatx4){0.f,0.f,0.f,0.f};
    #pragma unroll
    for (int ks = 0; ks < 4; ks++) {
      #pragma unroll
      for (int ct = 0; ct < 4; ct++) {
        bf16x8 kf = *(const bf16x8*)(kb0 + (size_t)(mbase + ct*16 + c)*CC + ks*32 + quad*8);
        S[0][ct] = __builtin_amdgcn_mfma_f32_16x16x32_bf16(qa[0][ks], kf, S[0][ct], 0, 0, 0);
        S[1][ct] = __builtin_amdgcn_mfma_f32_16x16x32_bf16(qa[1][ks], kf, S[1][ct], 0, 0, 0);
      }
    }
    #pragma unroll
    for (int rt = 0; rt < 2; rt++) {
      #pragma unroll
      for (int ct = 0; ct < 4; ct++) {
        float e0 = __expf(S[rt][ct][0]);
        float e1 = __expf(S[rt][ct][1]);
        float e2 = __expf(S[rt][ct][2]);
        float e3 = __expf(S[rt][ct][3]);
        lsum[rt][0] += e0; lsum[rt][1] += e1;
        lsum[rt][2] += e2; lsum[rt][3] += e3;
        bool odd = (c & 1);
        float s01 = odd ? e0 : e1;
        float g01 = __shfl_xor(s01, 1);
        unsigned lo0 = __float_as_uint(odd ? g01 : e0);
        unsigned hi0 = __float_as_uint(odd ? e1 : g01);
        unsigned p0 = (hi0 & 0xffff0000u) | (lo0 >> 16);
        float s23 = odd ? e2 : e3;
        float g23 = __shfl_xor(s23, 1);
        unsigned lo1 = __float_as_uint(odd ? g23 : e2);
        unsigned hi1 = __float_as_uint(odd ? e3 : g23);
        unsigned p1 = (hi1 & 0xffff0000u) | (lo1 >> 16);
        int colpair = ct*16 + (c & ~1);
        int rowA = rt*16 + quad*4 + (odd ? 1 : 0);
        int rowB = rt*16 + quad*4 + (odd ? 3 : 2);
        *(unsigned*)&Pl[rowA][colpair] = p0;
        *(unsigned*)&Pl[rowB][colpair] = p1;
      }
    }
    #pragma unroll
    for (int ks2 = 0; ks2 < 2; ks2++) {
      bf16x8 pa0 = *(const bf16x8*)(&Pl[c     ][ks2*32 + quad*8]);
      bf16x8 pa1 = *(const bf16x8*)(&Pl[16 + c][ks2*32 + quad*8]);
      #pragma unroll
      for (int ct = 0; ct < 8; ct++) {
        bf16x8 vf = *(const bf16x8*)(vb0 + (size_t)(ct*16 + c)*NN + mbase + ks2*32 + quad*8);
        O[0][ct] = __builtin_amdgcn_mfma_f32_16x16x32_bf16(pa0, vf, O[0][ct], 0, 0, 0);
        O[1][ct] = __builtin_amdgcn_mfma_f32_16x16x32_bf16(pa1, vf, O[1][ct], 0, 0, 0);
      }
    }
  }

  // ---- epilogue: l across 16 col-lanes; O across 4 waves (bf16 LDS, union w/ Pl) ----
  #pragma unroll
  for (int rt = 0; rt < 2; rt++)
    #pragma unroll
    for (int r = 0; r < 4; r++) {
      float vsum = lsum[rt][r];
      vsum += __shfl_xor(vsum, 1);
      vsum += __shfl_xor(vsum, 2);
      vsum += __shfl_xor(vsum, 4);
      vsum += __shfl_xor(vsum, 8);
      if (c == 0) lred[w][rt*16 + quad*4 + r] = vsum;
    }
  __syncthreads();   // all waves done reading their Pl before obf overwrites
  #pragma unroll
  for (int rt = 0; rt < 2; rt++)
    #pragma unroll
    for (int ct = 0; ct < 8; ct++)
      #pragma unroll
      for (int r = 0; r < 4; r++)
        shmem[w][rt*16 + quad*4 + r][ct*16 + c] = f2bf(O[rt][ct][r]);
  __syncthreads();
  size_t pbase = (size_t)(kh*BB + b)*NN + row0;
  if (t < 32)
    lpart[pbase + t] = lred[0][t] + lred[1][t] + lred[2][t] + lred[3][t];
  int rr = t >> 3, c0 = (t & 7) * 16;
  unsigned pk[8];
  #pragma unroll
  for (int j2 = 0; j2 < 8; j2++) {
    int cc0 = c0 + j2*2;
    float v0 = bf2f(shmem[0][rr][cc0])   + bf2f(shmem[1][rr][cc0])
             + bf2f(shmem[2][rr][cc0])   + bf2f(shmem[3][rr][cc0]);
    float v1 = bf2f(shmem[0][rr][cc0+1]) + bf2f(shmem[1][rr][cc0+1])
             + bf2f(shmem[2][rr][cc0+1]) + bf2f(shmem[3][rr][cc0+1]);
    pk[j2] = (unsigned)f2bf(v0) | ((unsigned)f2bf(v1) << 16);
  }
  uint4* od = (uint4*)(Opart + (pbase + rr)*CC + c0);
  od[0] = make_uint4(pk[0], pk[1], pk[2], pk[3]);
  od[1] = make_uint4(pk[4], pk[5], pk[6], pk[7]);
}

// ---- combine 4 partials + normalize + proj (MFMA) + bias + residual -> out [B,C,N] ----
__global__ __launch_bounds__(256, 2) void combine_kernel(
    const unsigned short* __restrict__ Opart, const float* __restrict__ lpart,
    const unsigned short* __restrict__ wpb, const float* __restrict__ bp,
    const float* __restrict__ x, float* __restrict__ out) {
  int b = blockIdx.y, n0 = blockIdx.x * 32;
  int t = threadIdx.x;
  __shared__ unsigned short hs[32][130];   // normalized attn output, bf16
  __shared__ float ps[32][132];            // proj result staging
  __shared__ float linv[32];
  if (t < 32) {
    float l = 0.f;
    #pragma unroll
    for (int kh = 0; kh < KSPLIT; kh++)
      l += lpart[((size_t)(kh*BB + b))*NN + n0 + t];
    linv[t] = 1.f / l;
  }
  __syncthreads();
  #pragma unroll
  for (int j = 0; j < 16; j++) {
    int idx = j*256 + t;
    int n = idx >> 7, c2 = idx & 127;
    float o = 0.f;
    #pragma unroll
    for (int kh = 0; kh < KSPLIT; kh++)
      o += bf2f(Opart[((size_t)(kh*BB + b)*NN + n0 + n)*CC + c2]);
    hs[n][c2] = f2bf(o * linv[n]);
  }
  __syncthreads();
  int w = t >> 6, lane = t & 63, quad = lane >> 4, c = lane & 15;
  int o0 = w * 32;
  floatx4 acc[2][2];
  #pragma unroll
  for (int rt = 0; rt < 2; rt++)
    #pragma unroll
    for (int ct = 0; ct < 2; ct++) acc[rt][ct] = (floatx4){0.f,0.f,0.f,0.f};
  #pragma unroll
  for (int ks = 0; ks < 4; ks++) {
    bf16x8 af[2];
    af[0] = *(const bf16x8*)&hs[c     ][ks*32 + quad*8];
    af[1] = *(const bf16x8*)&hs[16 + c][ks*32 + quad*8];
    #pragma unroll
    for (int ct = 0; ct < 2; ct++) {
      bf16x8 bfr = *(const bf16x8*)(wpb + (size_t)(o0 + ct*16 + c)*CC + ks*32 + quad*8);
      acc[0][ct] = __builtin_amdgcn_mfma_f32_16x16x32_bf16(af[0], bfr, acc[0][ct], 0, 0, 0);
      acc[1][ct] = __builtin_amdgcn_mfma_f32_16x16x32_bf16(af[1], bfr, acc[1][ct], 0, 0, 0);
    }
  }
  #pragma unroll
  for (int rt = 0; rt < 2; rt++)
    #pragma unroll
    for (int ct = 0; ct < 2; ct++)
      #pragma unroll
      for (int r = 0; r < 4; r++)
        ps[rt*16 + quad*4 + r][o0 + ct*16 + c] = acc[rt][ct][r];
  __syncthreads();
  int o = t >> 1, nh = (t & 1) * 16;
  float bi = bp[o];
  const float* xr = x + ((size_t)b*CC + o)*NN + n0 + nh;
  float* orow = out + ((size_t)b*CC + o)*NN + n0 + nh;
  #pragma unroll
  for (int j4 = 0; j4 < 4; j4++) {
    float4 xv = ((const float4*)xr)[j4];
    float4 ov;
    ov.x = xv.x + ps[nh + j4*4 + 0][o] + bi;
    ov.y = xv.y + ps[nh + j4*4 + 1][o] + bi;
    ov.z = xv.z + ps[nh + j4*4 + 2][o] + bi;
    ov.w = xv.w + ps[nh + j4*4 + 3][o] + bi;
    ((float4*)orow)[j4] = ov;
  }
}

extern "C" void kernel_launch(void* const* d_in, const int* in_sizes, int n_in,
                              void* d_out, int out_size, void* d_ws, size_t ws_size,
                              hipStream_t stream) {
  const float* x    = (const float*)d_in[0];
  const float* gn_w = (const float*)d_in[1];
  const float* gn_b = (const float*)d_in[2];
  const float* wq   = (const float*)d_in[3];
  const float* bq   = (const float*)d_in[4];
  const float* wk   = (const float*)d_in[5];
  const float* bk   = (const float*)d_in[6];
  const float* wv   = (const float*)d_in[7];
  const float* bv   = (const float*)d_in[8];
  const float* wp   = (const float*)d_in[9];
  const float* bp   = (const float*)d_in[10];
  float* out = (float*)d_out;

  char* ws = (char*)d_ws;
  float2*         stats = (float2*)(ws);                       // 2048 B
  float*          ab_a  = (float*)(ws + 2048);                 // 1024 B
  float*          ab_b  = (float*)(ws + 3072);                 // 1024 B
  float*          bqs   = (float*)(ws + 4096);                 // 512 B
  unsigned short* wqb   = (unsigned short*)(ws + 8192);        // 32 KiB each
  unsigned short* wkb   = (unsigned short*)(ws + 8192 + 32768);
  unsigned short* wvb   = (unsigned short*)(ws + 8192 + 65536);
  unsigned short* wpb   = (unsigned short*)(ws + 8192 + 98304);
  unsigned short* qb    = (unsigned short*)(ws + 262144);                  // 2 MiB
  unsigned short* kb    = (unsigned short*)(ws + 262144 + 2097152);        // 2 MiB
  unsigned short* vb    = (unsigned short*)(ws + 262144 + 2*2097152);      // 2 MiB
  unsigned short* Opart = (unsigned short*)(ws + 262144 + 3*2097152);      // 8 MiB
  float*          lpart = (float*)(ws + 262144 + 3*2097152 + 8388608);     // 128 KiB

  gn_stats_kernel<<<dim3(256), 256, 0, stream>>>(x, stats);
  prep_kernel    <<<dim3(65), 256, 0, stream>>>(stats, gn_w, gn_b, wq, bq, wk, wv, wp,
                                                ab_a, ab_b, bqs, wqb, wkb, wvb, wpb);
  qkv_kernel     <<<dim3(NN/32, BB, 3), 256, 0, stream>>>(x, ab_a, ab_b, wqb, wkb, wvb,
                                                          bqs, bk, bv, qb, kb, vb);
  attn_kernel    <<<dim3(NN/32, KSPLIT, BB), 256, 0, stream>>>(qb, kb, vb, Opart, lpart);
  combine_kernel <<<dim3(NN/32, BB), 256, 0, stream>>>(Opart, lpart, wpb, bp, x, out);
}

// Round 5
// 134.577 us; speedup vs baseline: 1.7852x; 1.7852x over previous
//
#include <hip/hip_runtime.h>
#include <math.h>

#define CC 128
#define NN 4096   // 16*16*16
#define BB 2
#define NGROUPS 32
#define CPG 4
#define GSIZE (CPG*NN)          // 16384 elements per (b, group)
#define KSPLIT 2

typedef __attribute__((ext_vector_type(8))) __bf16 bf16x8;
typedef __attribute__((ext_vector_type(4))) float floatx4;

__device__ __forceinline__ unsigned short f2bf(float f) {
  union { float f; unsigned u; } v; v.f = f;
  unsigned r = v.u + 0x7fff + ((v.u >> 16) & 1);   // RNE
  return (unsigned short)(r >> 16);
}
__device__ __forceinline__ float bf2f(unsigned short u) {
  return __uint_as_float(((unsigned)u) << 16);
}

// Tiled layouts (per batch, NN*CC elements):
//  Q/K: elem(n,ch) at (n>>4)*2048 + (ch>>5)*512 + (n&15)*32 + (ch&31)
//  V:   elem(ch,m) at (m>>5)*4096 + (ch>>4)*512 + (ch&15)*32 + (m&31)
// Both make every MFMA fragment load a contiguous 1KB per wave instruction.

// ---- stage 1: per-(b,g,chunk) partial sums. 256 blocks x 256 thr ----
__global__ void gn_stats_kernel(const float* __restrict__ x, float2* __restrict__ stats) {
  int bid = blockIdx.x;
  int t = threadIdx.x;
  const float4* base = (const float4*)(x + (size_t)bid * 4096);
  float4 v = base[t];
  float s  = v.x + v.y + v.z + v.w;
  float ss = v.x*v.x + v.y*v.y + v.z*v.z + v.w*v.w;
  #pragma unroll
  for (int off = 1; off < 64; off <<= 1) {
    s  += __shfl_xor(s, off);
    ss += __shfl_xor(ss, off);
  }
  __shared__ float sred[4], ssred[4];
  if ((t & 63) == 0) { sred[t >> 6] = s; ssred[t >> 6] = ss; }
  __syncthreads();
  if (t == 0)
    stats[bid] = make_float2(sred[0]+sred[1]+sred[2]+sred[3],
                             ssred[0]+ssred[1]+ssred[2]+ssred[3]);
}

// ---- stage 2 (65 blocks): 0-63 convert weights f32->bf16; 64 finalizes GN coeffs ----
__global__ void prep_kernel(const float2* __restrict__ stats,
                            const float* __restrict__ gamma, const float* __restrict__ beta,
                            const float* __restrict__ wq, const float* __restrict__ bq,
                            const float* __restrict__ wk, const float* __restrict__ wv,
                            const float* __restrict__ wp,
                            float* __restrict__ ab_a, float* __restrict__ ab_b,
                            float* __restrict__ bqs,
                            unsigned short* __restrict__ wqb, unsigned short* __restrict__ wkb,
                            unsigned short* __restrict__ wvb, unsigned short* __restrict__ wpb) {
  const float sc = 0.08838834764831845f;   // 128^-0.5, folded into wq/bq
  int t = threadIdx.x;
  if (blockIdx.x == 64) {
    if (t < BB*NGROUPS) {
      float su = 0.f, ssq = 0.f;
      #pragma unroll
      for (int j = 0; j < 4; j++) { float2 p = stats[t*4 + j]; su += p.x; ssq += p.y; }
      float mean = su * (1.0f/GSIZE);
      float var  = ssq * (1.0f/GSIZE) - mean*mean;
      float rstd = rsqrtf(var + 1e-5f);
      int b = t / NGROUPS, g = t % NGROUPS;
      #pragma unroll
      for (int j = 0; j < 4; j++) {
        int c = g*4 + j;
        float a = rstd * gamma[c];
        ab_a[b*CC + c] = a;
        ab_b[b*CC + c] = beta[c] - mean * a;
      }
    }
    if (t < CC) bqs[t] = bq[t] * sc;
  } else {
    int i = blockIdx.x * 256 + t;        // float4 index; 4096 per weight
    int id = i >> 12, local = i & 4095;
    const float* src = id==0 ? wq : id==1 ? wk : id==2 ? wv : wp;
    unsigned short* dst = id==0 ? wqb : id==1 ? wkb : id==2 ? wvb : wpb;
    float s = (id == 0) ? sc : 1.0f;
    float4 v = ((const float4*)src)[local];
    unsigned p0 = (unsigned)f2bf(v.x*s) | ((unsigned)f2bf(v.y*s) << 16);
    unsigned p1 = (unsigned)f2bf(v.z*s) | ((unsigned)f2bf(v.w*s) << 16);
    ((uint2*)dst)[local] = make_uint2(p0, p1);
  }
}

// ---- q/k/v via MFMA, GN on the fly. q,k -> tiled QK layout; v -> tiled V layout ----
__global__ __launch_bounds__(256, 2) void qkv_kernel(
    const float* __restrict__ x,
    const float* __restrict__ ab_a, const float* __restrict__ ab_b,
    const unsigned short* __restrict__ wqb, const unsigned short* __restrict__ wkb,
    const unsigned short* __restrict__ wvb,
    const float* __restrict__ bqs, const float* __restrict__ bk, const float* __restrict__ bv,
    unsigned short* __restrict__ q, unsigned short* __restrict__ k, unsigned short* __restrict__ v) {
  int z = blockIdx.z, b = blockIdx.y, n0 = blockIdx.x * 32;
  const unsigned short* wsel = z==0 ? wqb : z==1 ? wkb : wvb;
  const float* bias          = z==0 ? bqs : z==1 ? bk  : bv;
  unsigned short* outp       = z==0 ? q   : z==1 ? k   : v;
  __shared__ unsigned short hs[32][130];   // normalized x tile, bf16 [n][c]
  __shared__ unsigned short vs[32][136];   // transpose staging (z==2 only)
  int t = threadIdx.x;
  #pragma unroll
  for (int j = 0; j < 16; j++) {
    int idx = j*256 + t;
    int c = idx >> 5, n = idx & 31;
    float xv = x[((size_t)b*CC + c)*NN + n0 + n];     // coalesced along n
    hs[n][c] = f2bf(ab_a[b*CC + c]*xv + ab_b[b*CC + c]);
  }
  __syncthreads();
  int w = t >> 6, lane = t & 63, quad = lane >> 4, c = lane & 15;
  int o0 = w * 32;
  floatx4 acc[2][2];
  #pragma unroll
  for (int rt = 0; rt < 2; rt++)
    #pragma unroll
    for (int ct = 0; ct < 2; ct++) acc[rt][ct] = (floatx4){0.f,0.f,0.f,0.f};
  #pragma unroll
  for (int ks = 0; ks < 4; ks++) {
    bf16x8 af[2];
    af[0] = *(const bf16x8*)&hs[c     ][ks*32 + quad*8];
    af[1] = *(const bf16x8*)&hs[16 + c][ks*32 + quad*8];
    #pragma unroll
    for (int ct = 0; ct < 2; ct++) {
      bf16x8 bfr = *(const bf16x8*)(wsel + (size_t)(o0 + ct*16 + c)*CC + ks*32 + quad*8);
      acc[0][ct] = __builtin_amdgcn_mfma_f32_16x16x32_bf16(af[0], bfr, acc[0][ct], 0, 0, 0);
      acc[1][ct] = __builtin_amdgcn_mfma_f32_16x16x32_bf16(af[1], bfr, acc[1][ct], 0, 0, 0);
    }
  }
  if (z < 2) {
    // tiled QK store: (n>>4)*2048 + (ch>>5)*512 + (n&15)*32 + (ch&31)
    // ch = w*32 + ct*16 + c -> ch>>5 = w, ch&31 = ct*16+c
    size_t base = (size_t)b*NN*CC + ((size_t)(n0 >> 4))*2048 + w*512;
    #pragma unroll
    for (int ct = 0; ct < 2; ct++) {
      float bi = bias[o0 + ct*16 + c];
      #pragma unroll
      for (int rt = 0; rt < 2; rt++)
        #pragma unroll
        for (int r = 0; r < 4; r++)
          outp[base + rt*2048 + (quad*4 + r)*32 + ct*16 + c] = f2bf(acc[rt][ct][r] + bi);
    }
  } else {
    #pragma unroll
    for (int ct = 0; ct < 2; ct++) {
      float bi = bias[o0 + ct*16 + c];
      #pragma unroll
      for (int rt = 0; rt < 2; rt++)
        #pragma unroll
        for (int r = 0; r < 4; r++)
          vs[rt*16 + quad*4 + r][o0 + ct*16 + c] = f2bf(acc[rt][ct][r] + bi);
    }
    __syncthreads();
    // tiled V store: this block's 32 n's = m-tile (n0>>5).
    // elem(ch, m) at (n0>>5)*4096 + (ch>>4)*512 + (ch&15)*32 + (m&31)
    int ct = t >> 5;            // 0..7 channel tile
    int rem = t & 31;
    int c16 = rem >> 1;         // 0..15
    int m0 = (rem & 1) * 16;    // 0 or 16
    int ch = ct*16 + c16;
    unsigned pk[8];
    #pragma unroll
    for (int j2 = 0; j2 < 8; j2++) {
      unsigned lo = vs[m0 + j2*2    ][ch];
      unsigned hi = vs[m0 + j2*2 + 1][ch];
      pk[j2] = lo | (hi << 16);
    }
    uint4* dst = (uint4*)(outp + (size_t)b*NN*CC + ((size_t)(n0 >> 5))*4096 + ct*512 + c16*32 + m0);
    dst[0] = make_uint4(pk[0], pk[1], pk[2], pk[3]);
    dst[1] = make_uint4(pk[4], pk[5], pk[6], pk[7]);
  }
}

// ---- MFMA flash attention, split-K halves, no-max softmax, tiled coalesced loads ----
// grid (128 q-tiles, 2 k-halves, B) = 512 blocks, 2/CU. No main-loop barriers.
__global__ __launch_bounds__(256, 2) void attn_kernel(
    const unsigned short* __restrict__ qm,  // tiled QK layout, q-scale folded
    const unsigned short* __restrict__ km,  // tiled QK layout
    const unsigned short* __restrict__ vm,  // tiled V layout
    unsigned short* __restrict__ Opart,     // [KSPLIT][B][N][C] bf16, unnormalized
    float* __restrict__ lpart) {            // [KSPLIT][B][N] f32
  int b    = blockIdx.z;
  int kh   = blockIdx.y;
  int row0 = blockIdx.x * 32;
  int t    = threadIdx.x;
  int w    = t >> 6, lane = t & 63, quad = lane >> 4, c = lane & 15;

  // union: main loop uses first 32x72 shorts of each wave's region as Pl;
  // epilogue reuses the full 32x132 region as obf (barrier-guarded).
  __shared__ unsigned short shmem[4][32][132];
  __shared__ float lred[4][32];
  unsigned short (*Pl)[72] = (unsigned short (*)[72])&shmem[w][0][0];

  int fragoff = c*32 + quad*8;             // lane-linear within each 512-elem tile chunk

  bf16x8 qa[2][4];
  const unsigned short* qbase = qm + (size_t)b*NN*CC + ((size_t)(row0 >> 4))*2048;
  #pragma unroll
  for (int rt = 0; rt < 2; rt++)
    #pragma unroll
    for (int ks = 0; ks < 4; ks++)
      qa[rt][ks] = *(const bf16x8*)(qbase + rt*2048 + ks*512 + fragoff);

  floatx4 O[2][8];
  #pragma unroll
  for (int rt = 0; rt < 2; rt++)
    #pragma unroll
    for (int ct = 0; ct < 8; ct++) O[rt][ct] = (floatx4){0.f,0.f,0.f,0.f};
  float lsum[2][4];
  #pragma unroll
  for (int rt = 0; rt < 2; rt++)
    #pragma unroll
    for (int r = 0; r < 4; r++) lsum[rt][r] = 0.f;

  const unsigned short* kb0 = km + (size_t)b*NN*CC;
  const unsigned short* vb0 = vm + (size_t)b*NN*CC;

  for (int it = 0; it < NN/KSPLIT/256; it++) {
    int mbase = kh*(NN/KSPLIT) + it*256 + w*64;
    const unsigned short* kt = kb0 + ((size_t)(mbase >> 4))*2048;   // 4 n-tiles (ct)
    const unsigned short* vt = vb0 + ((size_t)(mbase >> 5))*4096;   // 2 m-tiles (ks2)
    floatx4 S[2][4];
    #pragma unroll
    for (int rt = 0; rt < 2; rt++)
      #pragma unroll
      for (int ct = 0; ct < 4; ct++) S[rt][ct] = (floatx4){0.f,0.f,0.f,0.f};
    #pragma unroll
    for (int ks = 0; ks < 4; ks++) {
      #pragma unroll
      for (int ct = 0; ct < 4; ct++) {
        bf16x8 kf = *(const bf16x8*)(kt + ct*2048 + ks*512 + fragoff);
        S[0][ct] = __builtin_amdgcn_mfma_f32_16x16x32_bf16(qa[0][ks], kf, S[0][ct], 0, 0, 0);
        S[1][ct] = __builtin_amdgcn_mfma_f32_16x16x32_bf16(qa[1][ks], kf, S[1][ct], 0, 0, 0);
      }
    }
    #pragma unroll
    for (int rt = 0; rt < 2; rt++) {
      #pragma unroll
      for (int ct = 0; ct < 4; ct++) {
        float e0 = __expf(S[rt][ct][0]);
        float e1 = __expf(S[rt][ct][1]);
        float e2 = __expf(S[rt][ct][2]);
        float e3 = __expf(S[rt][ct][3]);
        lsum[rt][0] += e0; lsum[rt][1] += e1;
        lsum[rt][2] += e2; lsum[rt][3] += e3;
        bool odd = (c & 1);
        float s01 = odd ? e0 : e1;
        float g01 = __shfl_xor(s01, 1);
        unsigned lo0 = __float_as_uint(odd ? g01 : e0);
        unsigned hi0 = __float_as_uint(odd ? e1 : g01);
        unsigned p0 = (hi0 & 0xffff0000u) | (lo0 >> 16);
        float s23 = odd ? e2 : e3;
        float g23 = __shfl_xor(s23, 1);
        unsigned lo1 = __float_as_uint(odd ? g23 : e2);
        unsigned hi1 = __float_as_uint(odd ? e3 : g23);
        unsigned p1 = (hi1 & 0xffff0000u) | (lo1 >> 16);
        int colpair = ct*16 + (c & ~1);
        int rowA = rt*16 + quad*4 + (odd ? 1 : 0);
        int rowB = rt*16 + quad*4 + (odd ? 3 : 2);
        *(unsigned*)&Pl[rowA][colpair] = p0;
        *(unsigned*)&Pl[rowB][colpair] = p1;
      }
    }
    #pragma unroll
    for (int ks2 = 0; ks2 < 2; ks2++) {
      bf16x8 pa0 = *(const bf16x8*)(&Pl[c     ][ks2*32 + quad*8]);
      bf16x8 pa1 = *(const bf16x8*)(&Pl[16 + c][ks2*32 + quad*8]);
      #pragma unroll
      for (int ct = 0; ct < 8; ct++) {
        bf16x8 vf = *(const bf16x8*)(vt + ks2*4096 + ct*512 + fragoff);
        O[0][ct] = __builtin_amdgcn_mfma_f32_16x16x32_bf16(pa0, vf, O[0][ct], 0, 0, 0);
        O[1][ct] = __builtin_amdgcn_mfma_f32_16x16x32_bf16(pa1, vf, O[1][ct], 0, 0, 0);
      }
    }
  }

  // ---- epilogue: l across 16 col-lanes; O across 4 waves (bf16 LDS, union w/ Pl) ----
  #pragma unroll
  for (int rt = 0; rt < 2; rt++)
    #pragma unroll
    for (int r = 0; r < 4; r++) {
      float vsum = lsum[rt][r];
      vsum += __shfl_xor(vsum, 1);
      vsum += __shfl_xor(vsum, 2);
      vsum += __shfl_xor(vsum, 4);
      vsum += __shfl_xor(vsum, 8);
      if (c == 0) lred[w][rt*16 + quad*4 + r] = vsum;
    }
  __syncthreads();
  #pragma unroll
  for (int rt = 0; rt < 2; rt++)
    #pragma unroll
    for (int ct = 0; ct < 8; ct++)
      #pragma unroll
      for (int r = 0; r < 4; r++)
        shmem[w][rt*16 + quad*4 + r][ct*16 + c] = f2bf(O[rt][ct][r]);
  __syncthreads();
  size_t pbase = (size_t)(kh*BB + b)*NN + row0;
  if (t < 32)
    lpart[pbase + t] = lred[0][t] + lred[1][t] + lred[2][t] + lred[3][t];
  int rr = t >> 3, c0 = (t & 7) * 16;
  unsigned pk[8];
  #pragma unroll
  for (int j2 = 0; j2 < 8; j2++) {
    int cc0 = c0 + j2*2;
    float v0 = bf2f(shmem[0][rr][cc0])   + bf2f(shmem[1][rr][cc0])
             + bf2f(shmem[2][rr][cc0])   + bf2f(shmem[3][rr][cc0]);
    float v1 = bf2f(shmem[0][rr][cc0+1]) + bf2f(shmem[1][rr][cc0+1])
             + bf2f(shmem[2][rr][cc0+1]) + bf2f(shmem[3][rr][cc0+1]);
    pk[j2] = (unsigned)f2bf(v0) | ((unsigned)f2bf(v1) << 16);
  }
  uint4* od = (uint4*)(Opart + (pbase + rr)*CC + c0);
  od[0] = make_uint4(pk[0], pk[1], pk[2], pk[3]);
  od[1] = make_uint4(pk[4], pk[5], pk[6], pk[7]);
}

// ---- combine partials + normalize + proj (MFMA) + bias + residual -> out [B,C,N] ----
__global__ __launch_bounds__(256, 2) void combine_kernel(
    const unsigned short* __restrict__ Opart, const float* __restrict__ lpart,
    const unsigned short* __restrict__ wpb, const float* __restrict__ bp,
    const float* __restrict__ x, float* __restrict__ out) {
  int b = blockIdx.y, n0 = blockIdx.x * 32;
  int t = threadIdx.x;
  __shared__ unsigned short hs[32][130];   // normalized attn output, bf16
  __shared__ float ps[32][132];            // proj result staging
  __shared__ float linv[32];
  if (t < 32) {
    float l = 0.f;
    #pragma unroll
    for (int kh = 0; kh < KSPLIT; kh++)
      l += lpart[((size_t)(kh*BB + b))*NN + n0 + t];
    linv[t] = 1.f / l;
  }
  __syncthreads();
  #pragma unroll
  for (int j = 0; j < 16; j++) {
    int idx = j*256 + t;
    int n = idx >> 7, c2 = idx & 127;
    float o = 0.f;
    #pragma unroll
    for (int kh = 0; kh < KSPLIT; kh++)
      o += bf2f(Opart[((size_t)(kh*BB + b)*NN + n0 + n)*CC + c2]);
    hs[n][c2] = f2bf(o * linv[n]);
  }
  __syncthreads();
  int w = t >> 6, lane = t & 63, quad = lane >> 4, c = lane & 15;
  int o0 = w * 32;
  floatx4 acc[2][2];
  #pragma unroll
  for (int rt = 0; rt < 2; rt++)
    #pragma unroll
    for (int ct = 0; ct < 2; ct++) acc[rt][ct] = (floatx4){0.f,0.f,0.f,0.f};
  #pragma unroll
  for (int ks = 0; ks < 4; ks++) {
    bf16x8 af[2];
    af[0] = *(const bf16x8*)&hs[c     ][ks*32 + quad*8];
    af[1] = *(const bf16x8*)&hs[16 + c][ks*32 + quad*8];
    #pragma unroll
    for (int ct = 0; ct < 2; ct++) {
      bf16x8 bfr = *(const bf16x8*)(wpb + (size_t)(o0 + ct*16 + c)*CC + ks*32 + quad*8);
      acc[0][ct] = __builtin_amdgcn_mfma_f32_16x16x32_bf16(af[0], bfr, acc[0][ct], 0, 0, 0);
      acc[1][ct] = __builtin_amdgcn_mfma_f32_16x16x32_bf16(af[1], bfr, acc[1][ct], 0, 0, 0);
    }
  }
  #pragma unroll
  for (int rt = 0; rt < 2; rt++)
    #pragma unroll
    for (int ct = 0; ct < 2; ct++)
      #pragma unroll
      for (int r = 0; r < 4; r++)
        ps[rt*16 + quad*4 + r][o0 + ct*16 + c] = acc[rt][ct][r];
  __syncthreads();
  int o = t >> 1, nh = (t & 1) * 16;
  float bi = bp[o];
  const float* xr = x + ((size_t)b*CC + o)*NN + n0 + nh;
  float* orow = out + ((size_t)b*CC + o)*NN + n0 + nh;
  #pragma unroll
  for (int j4 = 0; j4 < 4; j4++) {
    float4 xv = ((const float4*)xr)[j4];
    float4 ov;
    ov.x = xv.x + ps[nh + j4*4 + 0][o] + bi;
    ov.y = xv.y + ps[nh + j4*4 + 1][o] + bi;
    ov.z = xv.z + ps[nh + j4*4 + 2][o] + bi;
    ov.w = xv.w + ps[nh + j4*4 + 3][o] + bi;
    ((float4*)orow)[j4] = ov;
  }
}

extern "C" void kernel_launch(void* const* d_in, const int* in_sizes, int n_in,
                              void* d_out, int out_size, void* d_ws, size_t ws_size,
                              hipStream_t stream) {
  const float* x    = (const float*)d_in[0];
  const float* gn_w = (const float*)d_in[1];
  const float* gn_b = (const float*)d_in[2];
  const float* wq   = (const float*)d_in[3];
  const float* bq   = (const float*)d_in[4];
  const float* wk   = (const float*)d_in[5];
  const float* bk   = (const float*)d_in[6];
  const float* wv   = (const float*)d_in[7];
  const float* bv   = (const float*)d_in[8];
  const float* wp   = (const float*)d_in[9];
  const float* bp   = (const float*)d_in[10];
  float* out = (float*)d_out;

  char* ws = (char*)d_ws;
  float2*         stats = (float2*)(ws);                       // 2048 B
  float*          ab_a  = (float*)(ws + 2048);                 // 1024 B
  float*          ab_b  = (float*)(ws + 3072);                 // 1024 B
  float*          bqs   = (float*)(ws + 4096);                 // 512 B
  unsigned short* wqb   = (unsigned short*)(ws + 8192);        // 32 KiB each
  unsigned short* wkb   = (unsigned short*)(ws + 8192 + 32768);
  unsigned short* wvb   = (unsigned short*)(ws + 8192 + 65536);
  unsigned short* wpb   = (unsigned short*)(ws + 8192 + 98304);
  unsigned short* qb    = (unsigned short*)(ws + 262144);                  // 2 MiB
  unsigned short* kb    = (unsigned short*)(ws + 262144 + 2097152);        // 2 MiB
  unsigned short* vb    = (unsigned short*)(ws + 262144 + 2*2097152);      // 2 MiB
  unsigned short* Opart = (unsigned short*)(ws + 262144 + 3*2097152);      // 4 MiB
  float*          lpart = (float*)(ws + 262144 + 3*2097152 + 4194304);     // 64 KiB

  gn_stats_kernel<<<dim3(256), 256, 0, stream>>>(x, stats);
  prep_kernel    <<<dim3(65), 256, 0, stream>>>(stats, gn_w, gn_b, wq, bq, wk, wv, wp,
                                                ab_a, ab_b, bqs, wqb, wkb, wvb, wpb);
  qkv_kernel     <<<dim3(NN/32, BB, 3), 256, 0, stream>>>(x, ab_a, ab_b, wqb, wkb, wvb,
                                                          bqs, bk, bv, qb, kb, vb);
  attn_kernel    <<<dim3(NN/32, KSPLIT, BB), 256, 0, stream>>>(qb, kb, vb, Opart, lpart);
  combine_kernel <<<dim3(NN/32, BB), 256, 0, stream>>>(Opart, lpart, wpb, bp, x, out);
}